// Round 2
// baseline (788.141 us; speedup 1.0000x reference)
//
#include <hip/hip_runtime.h>

// GCN 3-layer: N=50000, E=1.6M, D_IN=256, H=128, D_OUT=64, fp32.
// Strategy: build CSR (grouped by dst) once per call, GEMM then CSR-SpMM per layer.
// NOTE: harness delivers integer inputs as int32 (edge_index int64 in reference
// becomes int32 on device) — read as const int*.

constexpr int DIN = 256;
constexpr int HID = 128;
constexpr int DOUT = 64;

// ---------- degree / dinv / CSR build ----------

__global__ void init_deg_kernel(int* __restrict__ deg, int n) {
  int i = blockIdx.x * blockDim.x + threadIdx.x;
  if (i < n) deg[i] = 1;  // self-loop
}

__global__ void deg_kernel(const int* __restrict__ dst, int* __restrict__ deg, int e) {
  int i = blockIdx.x * blockDim.x + threadIdx.x;
  if (i < e) atomicAdd(&deg[dst[i]], 1);
}

// Single-block exclusive scan of (deg-1) over n elements; also writes cursor and dinv.
__global__ __launch_bounds__(1024) void scan_kernel(const int* __restrict__ deg,
    int* __restrict__ row_start, int* __restrict__ cursor, float* __restrict__ dinv, int n) {
  __shared__ int sums[1024];
  int t = threadIdx.x;
  int per = (n + 1023) / 1024;
  int begin = t * per;
  int end = begin + per; if (end > n) end = n; if (begin > n) begin = n;
  int local = 0;
  for (int i = begin; i < end; ++i) local += deg[i] - 1;
  sums[t] = local;
  __syncthreads();
  // Hillis-Steele inclusive scan
  for (int off = 1; off < 1024; off <<= 1) {
    int v = (t >= off) ? sums[t - off] : 0;
    __syncthreads();
    sums[t] += v;
    __syncthreads();
  }
  int offset = (t == 0) ? 0 : sums[t - 1];
  for (int i = begin; i < end; ++i) {
    int d = deg[i];
    row_start[i] = offset;
    cursor[i] = offset;
    dinv[i] = rsqrtf((float)d);
    offset += d - 1;
  }
}

__global__ void fill_kernel(const int* __restrict__ src, const int* __restrict__ dst,
    const float* __restrict__ dinv, int* __restrict__ cursor,
    int* __restrict__ col, float* __restrict__ wgt, int e) {
  int i = blockIdx.x * blockDim.x + threadIdx.x;
  if (i >= e) return;
  int s = src[i];
  int d = dst[i];
  int pos = atomicAdd(&cursor[d], 1);
  col[pos] = s;
  wgt[pos] = dinv[s] * dinv[d];
}

// ---------- fp32 GEMM: C[n,F] = X[n,K] @ W[K,F] ----------
// Block computes 64 rows x F cols. 256 threads. LDS-staged X tile and W chunk.

template <int K, int F>
__global__ __launch_bounds__(256) void gemm_kernel(const float* __restrict__ X,
    const float* __restrict__ W, float* __restrict__ C, int n) {
  constexpr int KB = 32;             // k-chunk
  constexpr int CG = F / 4;          // col groups (float4)
  constexpr int RG = 256 / CG;       // row groups
  constexpr int RPT = 64 / RG;       // rows per thread
  constexpr int XS = KB + 4;         // padded X stride (36 floats = 144 B, 16B-aligned)
  __shared__ float Xs[64 * XS];
  __shared__ float Ws[KB * F];
  int tid = threadIdx.x;
  int cg = tid % CG;
  int rg = tid / CG;
  int row0 = blockIdx.x * 64;

  float4 acc[RPT];
#pragma unroll
  for (int r = 0; r < RPT; ++r) acc[r] = make_float4(0.f, 0.f, 0.f, 0.f);

  for (int k0 = 0; k0 < K; k0 += KB) {
    __syncthreads();
    // stage X tile [64 x KB]
    constexpr int XF4 = 64 * KB / 4;
    for (int idx = tid; idx < XF4; idx += 256) {
      int row = idx / (KB / 4);
      int k4 = idx % (KB / 4);
      float4 v = make_float4(0.f, 0.f, 0.f, 0.f);
      if (row0 + row < n)
        v = *(const float4*)(X + (size_t)(row0 + row) * K + k0 + k4 * 4);
      *(float4*)(Xs + row * XS + k4 * 4) = v;
    }
    // stage W chunk [KB x F]
    constexpr int WF4 = KB * F / 4;
    for (int idx = tid; idx < WF4; idx += 256) {
      int wr = idx / (F / 4);
      int wc4 = idx % (F / 4);
      *(float4*)(Ws + wr * F + wc4 * 4) =
          *(const float4*)(W + (size_t)(k0 + wr) * F + wc4 * 4);
    }
    __syncthreads();
#pragma unroll
    for (int kk = 0; kk < KB; kk += 4) {
      float4 xv[RPT];
#pragma unroll
      for (int r = 0; r < RPT; ++r)
        xv[r] = *(const float4*)(Xs + (rg * RPT + r) * XS + kk);
#pragma unroll
      for (int j = 0; j < 4; ++j) {
        float4 w = *(const float4*)(Ws + (kk + j) * F + cg * 4);
#pragma unroll
        for (int r = 0; r < RPT; ++r) {
          float xval = (j == 0) ? xv[r].x : (j == 1) ? xv[r].y : (j == 2) ? xv[r].z : xv[r].w;
          acc[r].x = fmaf(xval, w.x, acc[r].x);
          acc[r].y = fmaf(xval, w.y, acc[r].y);
          acc[r].z = fmaf(xval, w.z, acc[r].z);
          acc[r].w = fmaf(xval, w.w, acc[r].w);
        }
      }
    }
  }
#pragma unroll
  for (int r = 0; r < RPT; ++r) {
    int row = row0 + rg * RPT + r;
    if (row < n) *(float4*)(C + (size_t)row * F + cg * 4) = acc[r];
  }
}

// ---------- CSR SpMM: out[i] = dinv[i]^2*t[i] + sum_p wgt[p]*t[col[p]] + bias, opt ReLU ----------
// One wave (64 lanes) per destination node.

template <int F, bool RELU>
__global__ __launch_bounds__(256) void spmm_kernel(const float* __restrict__ t,
    const int* __restrict__ row_start, const int* __restrict__ deg,
    const int* __restrict__ col, const float* __restrict__ wgt,
    const float* __restrict__ dinv, const float* __restrict__ bias,
    float* __restrict__ out, int n) {
  int wid = (int)((blockIdx.x * 256u + threadIdx.x) >> 6);
  int lane = threadIdx.x & 63;
  if (wid >= n) return;
  int rs = row_start[wid];
  int cnt = deg[wid] - 1;
  float di = dinv[wid];
  float wself = di * di;

  if constexpr (F == 128) {
    const float2* trow = (const float2*)(t + (size_t)wid * F);
    float2 v = trow[lane];
    float ax = wself * v.x;
    float ay = wself * v.y;
    int p = rs, pe = rs + cnt;
    for (; p + 4 <= pe; p += 4) {
      int c0 = col[p], c1 = col[p + 1], c2 = col[p + 2], c3 = col[p + 3];
      float w0 = wgt[p], w1 = wgt[p + 1], w2 = wgt[p + 2], w3 = wgt[p + 3];
      float2 v0 = ((const float2*)(t + (size_t)c0 * F))[lane];
      float2 v1 = ((const float2*)(t + (size_t)c1 * F))[lane];
      float2 v2 = ((const float2*)(t + (size_t)c2 * F))[lane];
      float2 v3 = ((const float2*)(t + (size_t)c3 * F))[lane];
      ax = fmaf(w0, v0.x, ax); ay = fmaf(w0, v0.y, ay);
      ax = fmaf(w1, v1.x, ax); ay = fmaf(w1, v1.y, ay);
      ax = fmaf(w2, v2.x, ax); ay = fmaf(w2, v2.y, ay);
      ax = fmaf(w3, v3.x, ax); ay = fmaf(w3, v3.y, ay);
    }
    for (; p < pe; ++p) {
      int c = col[p];
      float w = wgt[p];
      float2 vv = ((const float2*)(t + (size_t)c * F))[lane];
      ax = fmaf(w, vv.x, ax); ay = fmaf(w, vv.y, ay);
    }
    ax += bias[2 * lane];
    ay += bias[2 * lane + 1];
    if constexpr (RELU) { ax = fmaxf(ax, 0.f); ay = fmaxf(ay, 0.f); }
    float2 o; o.x = ax; o.y = ay;
    ((float2*)(out + (size_t)wid * F))[lane] = o;
  } else {  // F == 64
    float a = wself * t[(size_t)wid * F + lane];
    int p = rs, pe = rs + cnt;
    for (; p + 4 <= pe; p += 4) {
      int c0 = col[p], c1 = col[p + 1], c2 = col[p + 2], c3 = col[p + 3];
      float w0 = wgt[p], w1 = wgt[p + 1], w2 = wgt[p + 2], w3 = wgt[p + 3];
      a = fmaf(w0, t[(size_t)c0 * F + lane], a);
      a = fmaf(w1, t[(size_t)c1 * F + lane], a);
      a = fmaf(w2, t[(size_t)c2 * F + lane], a);
      a = fmaf(w3, t[(size_t)c3 * F + lane], a);
    }
    for (; p < pe; ++p) a = fmaf(wgt[p], t[(size_t)col[p] * F + lane], a);
    a += bias[lane];
    if constexpr (RELU) a = fmaxf(a, 0.f);
    out[(size_t)wid * F + lane] = a;
  }
}

// ---------- launch ----------

extern "C" void kernel_launch(void* const* d_in, const int* in_sizes, int n_in,
                              void* d_out, int out_size, void* d_ws, size_t ws_size,
                              hipStream_t stream) {
  const float* x  = (const float*)d_in[0];
  const float* W1 = (const float*)d_in[1];
  const float* b1 = (const float*)d_in[2];
  const float* W2 = (const float*)d_in[3];
  const float* b2 = (const float*)d_in[4];
  const float* W3 = (const float*)d_in[5];
  const float* b3 = (const float*)d_in[6];
  const int* ei   = (const int*)d_in[7];  // harness delivers integers as int32

  int n = in_sizes[0] / DIN;
  int e = in_sizes[7] / 2;
  const int* src = ei;
  const int* dst = ei + e;

  char* ws = (char*)d_ws;
  size_t off = 0;
  auto alloc = [&](size_t bytes) -> void* {
    off = (off + 255) & ~(size_t)255;
    void* p = ws + off;
    off += bytes;
    return p;
  };
  int*   deg       = (int*)alloc((size_t)n * 4);
  float* dinv      = (float*)alloc((size_t)n * 4);
  int*   row_start = (int*)alloc((size_t)n * 4);
  int*   cursor    = (int*)alloc((size_t)n * 4);
  int*   col       = (int*)alloc((size_t)e * 4);
  float* wgt       = (float*)alloc((size_t)e * 4);
  float* A         = (float*)alloc((size_t)n * HID * 4);
  float* B         = (float*)alloc((size_t)n * HID * 4);
  (void)ws_size;

  int nb256 = (n + 255) / 256;
  int eb256 = (e + 255) / 256;
  int gemm_blocks = (n + 63) / 64;
  int spmm_blocks = (n + 3) / 4;  // 4 waves per 256-thread block, 1 wave/node

  init_deg_kernel<<<nb256, 256, 0, stream>>>(deg, n);
  deg_kernel<<<eb256, 256, 0, stream>>>(dst, deg, e);
  scan_kernel<<<1, 1024, 0, stream>>>(deg, row_start, cursor, dinv, n);
  fill_kernel<<<eb256, 256, 0, stream>>>(src, dst, dinv, cursor, col, wgt, e);

  // Layer 1: t = x @ W1 ; h1 = relu(agg(t) + b1)
  gemm_kernel<DIN, HID><<<gemm_blocks, 256, 0, stream>>>(x, W1, A, n);
  spmm_kernel<HID, true><<<spmm_blocks, 256, 0, stream>>>(A, row_start, deg, col, wgt, dinv, b1, B, n);
  // Layer 2
  gemm_kernel<HID, HID><<<gemm_blocks, 256, 0, stream>>>(B, W2, A, n);
  spmm_kernel<HID, true><<<spmm_blocks, 256, 0, stream>>>(A, row_start, deg, col, wgt, dinv, b2, B, n);
  // Layer 3 (no ReLU)
  gemm_kernel<HID, DOUT><<<gemm_blocks, 256, 0, stream>>>(B, W3, A, n);
  spmm_kernel<DOUT, false><<<spmm_blocks, 256, 0, stream>>>(A, row_start, deg, col, wgt, dinv, b3, (float*)d_out, n);
}

// Round 3
// 671.915 us; speedup vs baseline: 1.1730x; 1.1730x over previous
//
#include <hip/hip_runtime.h>

// GCN 3-layer: N=50000, E=1.6M, D_IN=256, H=128, D_OUT=64, fp32.
// CSR build (parallel scan) -> per-layer GEMM then CSR-SpMM.
// Weights dinv[s]*dinv[d] computed on the fly in SpMM (no wgt array).

constexpr int DIN = 256;
constexpr int HID = 128;
constexpr int DOUT = 64;

// ---------- degree ----------

__global__ void init_deg_kernel(int* __restrict__ deg, int n) {
  int i = blockIdx.x * blockDim.x + threadIdx.x;
  if (i < n) deg[i] = 1;  // self-loop
}

__global__ void deg_kernel(const int* __restrict__ dst, int* __restrict__ deg, int e) {
  int i = blockIdx.x * blockDim.x + threadIdx.x;
  if (i < e) atomicAdd(&deg[dst[i]], 1);
}

// ---------- 3-phase exclusive scan of (deg-1), 1024 elems / block ----------

// Phase A: per-block sums.
__global__ __launch_bounds__(256) void scanA_kernel(const int* __restrict__ deg,
    int* __restrict__ blocksum, int n) {
  __shared__ int sums[256];
  int t = threadIdx.x;
  int base = blockIdx.x * 1024 + t * 4;
  int local = 0;
#pragma unroll
  for (int k = 0; k < 4; ++k) {
    int i = base + k;
    if (i < n) local += deg[i] - 1;
  }
  sums[t] = local;
  __syncthreads();
  for (int off = 128; off > 0; off >>= 1) {
    if (t < off) sums[t] += sums[t + off];
    __syncthreads();
  }
  if (t == 0) blocksum[blockIdx.x] = sums[0];
}

// Phase B: single-wave exclusive scan of nb block sums (nb can exceed 64; chunked with carry).
__global__ __launch_bounds__(64) void scanB_kernel(int* __restrict__ blocksum, int nb) {
  int lane = threadIdx.x;
  int carry = 0;
  for (int base = 0; base < nb; base += 64) {
    int i = base + lane;
    int orig = (i < nb) ? blocksum[i] : 0;
    int v = orig;
#pragma unroll
    for (int off = 1; off < 64; off <<= 1) {
      int u = __shfl_up(v, off, 64);
      if (lane >= off) v += u;
    }
    int total = __shfl(v, 63, 64);
    if (i < nb) blocksum[i] = carry + v - orig;  // exclusive
    carry += total;
  }
}

// Phase C: per-block exclusive scan, add block offset, emit row_start/cursor/dinv.
__global__ __launch_bounds__(256) void scanC_kernel(const int* __restrict__ deg,
    const int* __restrict__ blocksum, int* __restrict__ row_start,
    int* __restrict__ cursor, float* __restrict__ dinv, int n) {
  __shared__ int sums[256];
  int t = threadIdx.x;
  int base = blockIdx.x * 1024 + t * 4;
  int d[4];
  int local = 0;
#pragma unroll
  for (int k = 0; k < 4; ++k) {
    int i = base + k;
    d[k] = (i < n) ? deg[i] : 1;
    if (i < n) local += d[k] - 1;
  }
  sums[t] = local;
  __syncthreads();
  // Hillis-Steele inclusive scan over 256 thread sums
  for (int off = 1; off < 256; off <<= 1) {
    int v = (t >= off) ? sums[t - off] : 0;
    __syncthreads();
    sums[t] += v;
    __syncthreads();
  }
  int run = blocksum[blockIdx.x] + sums[t] - local;  // exclusive offset for this thread
#pragma unroll
  for (int k = 0; k < 4; ++k) {
    int i = base + k;
    if (i < n) {
      row_start[i] = run;
      cursor[i] = run;
      dinv[i] = rsqrtf((float)d[k]);
      run += d[k] - 1;
    }
  }
}

// ---------- CSR fill (col only; weights computed in SpMM) ----------

__global__ void fill_kernel(const int* __restrict__ src, const int* __restrict__ dst,
    int* __restrict__ cursor, int* __restrict__ col, int e) {
  int i = blockIdx.x * blockDim.x + threadIdx.x;
  if (i >= e) return;
  int pos = atomicAdd(&cursor[dst[i]], 1);
  col[pos] = src[i];
}

// ---------- fp32 GEMM: C[n,F] = X[n,K] @ W[K,F] ----------

template <int K, int F>
__global__ __launch_bounds__(256) void gemm_kernel(const float* __restrict__ X,
    const float* __restrict__ W, float* __restrict__ C, int n) {
  constexpr int KB = 32;
  constexpr int CG = F / 4;
  constexpr int RG = 256 / CG;
  constexpr int RPT = 64 / RG;
  constexpr int XS = KB + 4;
  __shared__ float Xs[64 * XS];
  __shared__ float Ws[KB * F];
  int tid = threadIdx.x;
  int cg = tid % CG;
  int rg = tid / CG;
  int row0 = blockIdx.x * 64;

  float4 acc[RPT];
#pragma unroll
  for (int r = 0; r < RPT; ++r) acc[r] = make_float4(0.f, 0.f, 0.f, 0.f);

  for (int k0 = 0; k0 < K; k0 += KB) {
    __syncthreads();
    constexpr int XF4 = 64 * KB / 4;
    for (int idx = tid; idx < XF4; idx += 256) {
      int row = idx / (KB / 4);
      int k4 = idx % (KB / 4);
      float4 v = make_float4(0.f, 0.f, 0.f, 0.f);
      if (row0 + row < n)
        v = *(const float4*)(X + (size_t)(row0 + row) * K + k0 + k4 * 4);
      *(float4*)(Xs + row * XS + k4 * 4) = v;
    }
    constexpr int WF4 = KB * F / 4;
    for (int idx = tid; idx < WF4; idx += 256) {
      int wr = idx / (F / 4);
      int wc4 = idx % (F / 4);
      *(float4*)(Ws + wr * F + wc4 * 4) =
          *(const float4*)(W + (size_t)(k0 + wr) * F + wc4 * 4);
    }
    __syncthreads();
#pragma unroll
    for (int kk = 0; kk < KB; kk += 4) {
      float4 xv[RPT];
#pragma unroll
      for (int r = 0; r < RPT; ++r)
        xv[r] = *(const float4*)(Xs + (rg * RPT + r) * XS + kk);
#pragma unroll
      for (int j = 0; j < 4; ++j) {
        float4 w = *(const float4*)(Ws + (kk + j) * F + cg * 4);
#pragma unroll
        for (int r = 0; r < RPT; ++r) {
          float xval = (j == 0) ? xv[r].x : (j == 1) ? xv[r].y : (j == 2) ? xv[r].z : xv[r].w;
          acc[r].x = fmaf(xval, w.x, acc[r].x);
          acc[r].y = fmaf(xval, w.y, acc[r].y);
          acc[r].z = fmaf(xval, w.z, acc[r].z);
          acc[r].w = fmaf(xval, w.w, acc[r].w);
        }
      }
    }
  }
#pragma unroll
  for (int r = 0; r < RPT; ++r) {
    int row = row0 + rg * RPT + r;
    if (row < n) *(float4*)(C + (size_t)row * F + cg * 4) = acc[r];
  }
}

// ---------- CSR SpMM: out[i] = dinv[i]^2*t[i] + sum_p dinv[col]*dinv[i]*t[col] + b ----------
// One wave per destination node. col/dinv reads are wave-uniform -> scalar loads.

template <int F, bool RELU>
__global__ __launch_bounds__(256) void spmm_kernel(const float* __restrict__ t,
    const int* __restrict__ row_start, const int* __restrict__ deg,
    const int* __restrict__ col, const float* __restrict__ dinv,
    const float* __restrict__ bias, float* __restrict__ out, int n) {
  int wid = (int)((blockIdx.x * 256u + threadIdx.x) >> 6);
  int lane = threadIdx.x & 63;
  if (wid >= n) return;
  int rs = row_start[wid];
  int cnt = deg[wid] - 1;
  float di = dinv[wid];
  float wself = di * di;

  if constexpr (F == 128) {
    float2 v = ((const float2*)(t + (size_t)wid * F))[lane];
    float ax = wself * v.x;
    float ay = wself * v.y;
    int p = rs, pe = rs + cnt;
    for (; p + 4 <= pe; p += 4) {
      int c0 = col[p], c1 = col[p + 1], c2 = col[p + 2], c3 = col[p + 3];
      float w0 = di * dinv[c0], w1 = di * dinv[c1];
      float w2 = di * dinv[c2], w3 = di * dinv[c3];
      float2 v0 = ((const float2*)(t + (size_t)c0 * F))[lane];
      float2 v1 = ((const float2*)(t + (size_t)c1 * F))[lane];
      float2 v2 = ((const float2*)(t + (size_t)c2 * F))[lane];
      float2 v3 = ((const float2*)(t + (size_t)c3 * F))[lane];
      ax = fmaf(w0, v0.x, ax); ay = fmaf(w0, v0.y, ay);
      ax = fmaf(w1, v1.x, ax); ay = fmaf(w1, v1.y, ay);
      ax = fmaf(w2, v2.x, ax); ay = fmaf(w2, v2.y, ay);
      ax = fmaf(w3, v3.x, ax); ay = fmaf(w3, v3.y, ay);
    }
    for (; p < pe; ++p) {
      int c = col[p];
      float w = di * dinv[c];
      float2 vv = ((const float2*)(t + (size_t)c * F))[lane];
      ax = fmaf(w, vv.x, ax); ay = fmaf(w, vv.y, ay);
    }
    ax += bias[2 * lane];
    ay += bias[2 * lane + 1];
    if constexpr (RELU) { ax = fmaxf(ax, 0.f); ay = fmaxf(ay, 0.f); }
    float2 o; o.x = ax; o.y = ay;
    ((float2*)(out + (size_t)wid * F))[lane] = o;
  } else {  // F == 64
    float a = wself * t[(size_t)wid * F + lane];
    int p = rs, pe = rs + cnt;
    for (; p + 4 <= pe; p += 4) {
      int c0 = col[p], c1 = col[p + 1], c2 = col[p + 2], c3 = col[p + 3];
      float w0 = di * dinv[c0], w1 = di * dinv[c1];
      float w2 = di * dinv[c2], w3 = di * dinv[c3];
      a = fmaf(w0, t[(size_t)c0 * F + lane], a);
      a = fmaf(w1, t[(size_t)c1 * F + lane], a);
      a = fmaf(w2, t[(size_t)c2 * F + lane], a);
      a = fmaf(w3, t[(size_t)c3 * F + lane], a);
    }
    for (; p < pe; ++p) a = fmaf(di * dinv[col[p]], t[(size_t)col[p] * F + lane], a);
    a += bias[lane];
    if constexpr (RELU) a = fmaxf(a, 0.f);
    out[(size_t)wid * F + lane] = a;
  }
}

// ---------- launch ----------

extern "C" void kernel_launch(void* const* d_in, const int* in_sizes, int n_in,
                              void* d_out, int out_size, void* d_ws, size_t ws_size,
                              hipStream_t stream) {
  const float* x  = (const float*)d_in[0];
  const float* W1 = (const float*)d_in[1];
  const float* b1 = (const float*)d_in[2];
  const float* W2 = (const float*)d_in[3];
  const float* b2 = (const float*)d_in[4];
  const float* W3 = (const float*)d_in[5];
  const float* b3 = (const float*)d_in[6];
  const int* ei   = (const int*)d_in[7];  // harness delivers integers as int32

  int n = in_sizes[0] / DIN;
  int e = in_sizes[7] / 2;
  const int* src = ei;
  const int* dst = ei + e;

  char* ws = (char*)d_ws;
  size_t off = 0;
  auto alloc = [&](size_t bytes) -> void* {
    off = (off + 255) & ~(size_t)255;
    void* p = ws + off;
    off += bytes;
    return p;
  };
  int nscan = (n + 1023) / 1024;
  int*   deg       = (int*)alloc((size_t)n * 4);
  float* dinv      = (float*)alloc((size_t)n * 4);
  int*   row_start = (int*)alloc((size_t)n * 4);
  int*   cursor    = (int*)alloc((size_t)n * 4);
  int*   blocksum  = (int*)alloc((size_t)nscan * 4);
  int*   col       = (int*)alloc((size_t)e * 4);
  float* A         = (float*)alloc((size_t)n * HID * 4);
  float* B         = (float*)alloc((size_t)n * HID * 4);
  (void)ws_size;

  int nb256 = (n + 255) / 256;
  int eb256 = (e + 255) / 256;
  int gemm_blocks = (n + 63) / 64;
  int spmm_blocks = (n + 3) / 4;  // 4 waves / block, 1 wave / node

  init_deg_kernel<<<nb256, 256, 0, stream>>>(deg, n);
  deg_kernel<<<eb256, 256, 0, stream>>>(dst, deg, e);
  scanA_kernel<<<nscan, 256, 0, stream>>>(deg, blocksum, n);
  scanB_kernel<<<1, 64, 0, stream>>>(blocksum, nscan);
  scanC_kernel<<<nscan, 256, 0, stream>>>(deg, blocksum, row_start, cursor, dinv, n);
  fill_kernel<<<eb256, 256, 0, stream>>>(src, dst, cursor, col, e);

  gemm_kernel<DIN, HID><<<gemm_blocks, 256, 0, stream>>>(x, W1, A, n);
  spmm_kernel<HID, true><<<spmm_blocks, 256, 0, stream>>>(A, row_start, deg, col, dinv, b1, B, n);
  gemm_kernel<HID, HID><<<gemm_blocks, 256, 0, stream>>>(B, W2, A, n);
  spmm_kernel<HID, true><<<spmm_blocks, 256, 0, stream>>>(A, row_start, deg, col, dinv, b2, B, n);
  gemm_kernel<HID, DOUT><<<gemm_blocks, 256, 0, stream>>>(B, W3, A, n);
  spmm_kernel<DOUT, false><<<spmm_blocks, 256, 0, stream>>>(A, row_start, deg, col, dinv, b3, (float*)d_out, n);
}

// Round 4
// 570.787 us; speedup vs baseline: 1.3808x; 1.1772x over previous
//
#include <hip/hip_runtime.h>

// GCN 3-layer: N=50000, E=1.6M, D_IN=256, H=128, D_OUT=64, fp32.
// CSR build: ONE atomic pass (deg count, atomic return value = slot within row),
// parallel scan, then atomic-free scatter fill. Per layer: GEMM then CSR-SpMM.

constexpr int DIN = 256;
constexpr int HID = 128;
constexpr int DOUT = 64;

// ---------- degree + slot (single atomic pass) ----------

__global__ void init_deg_kernel(int* __restrict__ deg, int n) {
  int i = blockIdx.x * blockDim.x + threadIdx.x;
  if (i < n) deg[i] = 1;  // self-loop
}

__global__ void deg_slot_kernel(const int* __restrict__ dst, int* __restrict__ deg,
                                int* __restrict__ slot, int e) {
  int i = blockIdx.x * blockDim.x + threadIdx.x;
  if (i < e) slot[i] = atomicAdd(&deg[dst[i]], 1);  // old value in [1, deg-1]
}

// ---------- 3-phase exclusive scan of (deg-1), 1024 elems / block ----------

__global__ __launch_bounds__(256) void scanA_kernel(const int* __restrict__ deg,
    int* __restrict__ blocksum, int n) {
  __shared__ int sums[256];
  int t = threadIdx.x;
  int base = blockIdx.x * 1024 + t * 4;
  int local = 0;
#pragma unroll
  for (int k = 0; k < 4; ++k) {
    int i = base + k;
    if (i < n) local += deg[i] - 1;
  }
  sums[t] = local;
  __syncthreads();
  for (int off = 128; off > 0; off >>= 1) {
    if (t < off) sums[t] += sums[t + off];
    __syncthreads();
  }
  if (t == 0) blocksum[blockIdx.x] = sums[0];
}

__global__ __launch_bounds__(64) void scanB_kernel(int* __restrict__ blocksum, int nb) {
  int lane = threadIdx.x;
  int carry = 0;
  for (int base = 0; base < nb; base += 64) {
    int i = base + lane;
    int orig = (i < nb) ? blocksum[i] : 0;
    int v = orig;
#pragma unroll
    for (int off = 1; off < 64; off <<= 1) {
      int u = __shfl_up(v, off, 64);
      if (lane >= off) v += u;
    }
    int total = __shfl(v, 63, 64);
    if (i < nb) blocksum[i] = carry + v - orig;  // exclusive
    carry += total;
  }
}

__global__ __launch_bounds__(256) void scanC_kernel(const int* __restrict__ deg,
    const int* __restrict__ blocksum, int* __restrict__ row_start,
    float* __restrict__ dinv, int n) {
  __shared__ int sums[256];
  int t = threadIdx.x;
  int base = blockIdx.x * 1024 + t * 4;
  int d[4];
  int local = 0;
#pragma unroll
  for (int k = 0; k < 4; ++k) {
    int i = base + k;
    d[k] = (i < n) ? deg[i] : 1;
    if (i < n) local += d[k] - 1;
  }
  sums[t] = local;
  __syncthreads();
  for (int off = 1; off < 256; off <<= 1) {
    int v = (t >= off) ? sums[t - off] : 0;
    __syncthreads();
    sums[t] += v;
    __syncthreads();
  }
  int run = blocksum[blockIdx.x] + sums[t] - local;  // exclusive offset
#pragma unroll
  for (int k = 0; k < 4; ++k) {
    int i = base + k;
    if (i < n) {
      row_start[i] = run;
      dinv[i] = rsqrtf((float)d[k]);
      run += d[k] - 1;
    }
  }
}

// ---------- CSR fill: atomic-free scatter using precomputed slot ----------

__global__ void fill_kernel(const int* __restrict__ src, const int* __restrict__ dst,
    const int* __restrict__ slot, const int* __restrict__ row_start,
    int* __restrict__ col, int e) {
  int i = blockIdx.x * blockDim.x + threadIdx.x;
  if (i >= e) return;
  col[row_start[dst[i]] + slot[i] - 1] = src[i];
}

// ---------- fp32 GEMM: C[n,F] = X[n,K] @ W[K,F] ----------

template <int K, int F>
__global__ __launch_bounds__(256) void gemm_kernel(const float* __restrict__ X,
    const float* __restrict__ W, float* __restrict__ C, int n) {
  constexpr int KB = 32;
  constexpr int CG = F / 4;
  constexpr int RG = 256 / CG;
  constexpr int RPT = 64 / RG;
  constexpr int XS = KB + 4;
  __shared__ float Xs[64 * XS];
  __shared__ float Ws[KB * F];
  int tid = threadIdx.x;
  int cg = tid % CG;
  int rg = tid / CG;
  int row0 = blockIdx.x * 64;

  float4 acc[RPT];
#pragma unroll
  for (int r = 0; r < RPT; ++r) acc[r] = make_float4(0.f, 0.f, 0.f, 0.f);

  for (int k0 = 0; k0 < K; k0 += KB) {
    __syncthreads();
    constexpr int XF4 = 64 * KB / 4;
    for (int idx = tid; idx < XF4; idx += 256) {
      int row = idx / (KB / 4);
      int k4 = idx % (KB / 4);
      float4 v = make_float4(0.f, 0.f, 0.f, 0.f);
      if (row0 + row < n)
        v = *(const float4*)(X + (size_t)(row0 + row) * K + k0 + k4 * 4);
      *(float4*)(Xs + row * XS + k4 * 4) = v;
    }
    constexpr int WF4 = KB * F / 4;
    for (int idx = tid; idx < WF4; idx += 256) {
      int wr = idx / (F / 4);
      int wc4 = idx % (F / 4);
      *(float4*)(Ws + wr * F + wc4 * 4) =
          *(const float4*)(W + (size_t)(k0 + wr) * F + wc4 * 4);
    }
    __syncthreads();
#pragma unroll
    for (int kk = 0; kk < KB; kk += 4) {
      float4 xv[RPT];
#pragma unroll
      for (int r = 0; r < RPT; ++r)
        xv[r] = *(const float4*)(Xs + (rg * RPT + r) * XS + kk);
#pragma unroll
      for (int j = 0; j < 4; ++j) {
        float4 w = *(const float4*)(Ws + (kk + j) * F + cg * 4);
#pragma unroll
        for (int r = 0; r < RPT; ++r) {
          float xval = (j == 0) ? xv[r].x : (j == 1) ? xv[r].y : (j == 2) ? xv[r].z : xv[r].w;
          acc[r].x = fmaf(xval, w.x, acc[r].x);
          acc[r].y = fmaf(xval, w.y, acc[r].y);
          acc[r].z = fmaf(xval, w.z, acc[r].z);
          acc[r].w = fmaf(xval, w.w, acc[r].w);
        }
      }
    }
  }
#pragma unroll
  for (int r = 0; r < RPT; ++r) {
    int row = row0 + rg * RPT + r;
    if (row < n) *(float4*)(C + (size_t)row * F + cg * 4) = acc[r];
  }
}

// ---------- CSR SpMM: out[i] = dinv[i]^2*t[i] + sum_p dinv[col]*dinv[i]*t[col] + b ----------
// One wave per destination node; unroll 8 for memory-level parallelism.

template <int F, bool RELU>
__global__ __launch_bounds__(256) void spmm_kernel(const float* __restrict__ t,
    const int* __restrict__ row_start, const int* __restrict__ deg,
    const int* __restrict__ col, const float* __restrict__ dinv,
    const float* __restrict__ bias, float* __restrict__ out, int n) {
  int wid = (int)((blockIdx.x * 256u + threadIdx.x) >> 6);
  int lane = threadIdx.x & 63;
  if (wid >= n) return;
  int rs = row_start[wid];
  int cnt = deg[wid] - 1;
  float di = dinv[wid];
  float wself = di * di;

  if constexpr (F == 128) {
    float2 v = ((const float2*)(t + (size_t)wid * F))[lane];
    float ax = wself * v.x;
    float ay = wself * v.y;
    int p = rs, pe = rs + cnt;
    for (; p + 8 <= pe; p += 8) {
      int c[8];
      float w[8];
      float2 vv[8];
#pragma unroll
      for (int j = 0; j < 8; ++j) c[j] = col[p + j];
#pragma unroll
      for (int j = 0; j < 8; ++j) vv[j] = ((const float2*)(t + (size_t)c[j] * F))[lane];
#pragma unroll
      for (int j = 0; j < 8; ++j) w[j] = di * dinv[c[j]];
#pragma unroll
      for (int j = 0; j < 8; ++j) {
        ax = fmaf(w[j], vv[j].x, ax);
        ay = fmaf(w[j], vv[j].y, ay);
      }
    }
    for (; p < pe; ++p) {
      int c = col[p];
      float w = di * dinv[c];
      float2 vv = ((const float2*)(t + (size_t)c * F))[lane];
      ax = fmaf(w, vv.x, ax); ay = fmaf(w, vv.y, ay);
    }
    ax += bias[2 * lane];
    ay += bias[2 * lane + 1];
    if constexpr (RELU) { ax = fmaxf(ax, 0.f); ay = fmaxf(ay, 0.f); }
    float2 o; o.x = ax; o.y = ay;
    ((float2*)(out + (size_t)wid * F))[lane] = o;
  } else {  // F == 64
    float a = wself * t[(size_t)wid * F + lane];
    int p = rs, pe = rs + cnt;
    for (; p + 8 <= pe; p += 8) {
      int c[8];
      float w[8];
      float vv[8];
#pragma unroll
      for (int j = 0; j < 8; ++j) c[j] = col[p + j];
#pragma unroll
      for (int j = 0; j < 8; ++j) vv[j] = t[(size_t)c[j] * F + lane];
#pragma unroll
      for (int j = 0; j < 8; ++j) w[j] = di * dinv[c[j]];
#pragma unroll
      for (int j = 0; j < 8; ++j) a = fmaf(w[j], vv[j], a);
    }
    for (; p < pe; ++p) a = fmaf(di * dinv[col[p]], t[(size_t)col[p] * F + lane], a);
    a += bias[lane];
    if constexpr (RELU) a = fmaxf(a, 0.f);
    out[(size_t)wid * F + lane] = a;
  }
}

// ---------- launch ----------

extern "C" void kernel_launch(void* const* d_in, const int* in_sizes, int n_in,
                              void* d_out, int out_size, void* d_ws, size_t ws_size,
                              hipStream_t stream) {
  const float* x  = (const float*)d_in[0];
  const float* W1 = (const float*)d_in[1];
  const float* b1 = (const float*)d_in[2];
  const float* W2 = (const float*)d_in[3];
  const float* b2 = (const float*)d_in[4];
  const float* W3 = (const float*)d_in[5];
  const float* b3 = (const float*)d_in[6];
  const int* ei   = (const int*)d_in[7];  // harness delivers integers as int32

  int n = in_sizes[0] / DIN;
  int e = in_sizes[7] / 2;
  const int* src = ei;
  const int* dst = ei + e;

  char* ws = (char*)d_ws;
  size_t off = 0;
  auto alloc = [&](size_t bytes) -> void* {
    off = (off + 255) & ~(size_t)255;
    void* p = ws + off;
    off += bytes;
    return p;
  };
  int nscan = (n + 1023) / 1024;
  int*   deg       = (int*)alloc((size_t)n * 4);
  float* dinv      = (float*)alloc((size_t)n * 4);
  int*   row_start = (int*)alloc((size_t)n * 4);
  int*   blocksum  = (int*)alloc((size_t)nscan * 4);
  int*   slot      = (int*)alloc((size_t)e * 4);
  int*   col       = (int*)alloc((size_t)e * 4);
  float* A         = (float*)alloc((size_t)n * HID * 4);
  float* B         = (float*)alloc((size_t)n * HID * 4);
  (void)ws_size;

  int nb256 = (n + 255) / 256;
  int eb256 = (e + 255) / 256;
  int gemm_blocks = (n + 63) / 64;
  int spmm_blocks = (n + 3) / 4;  // 4 waves / block, 1 wave / node

  init_deg_kernel<<<nb256, 256, 0, stream>>>(deg, n);
  deg_slot_kernel<<<eb256, 256, 0, stream>>>(dst, deg, slot, e);
  scanA_kernel<<<nscan, 256, 0, stream>>>(deg, blocksum, n);
  scanB_kernel<<<1, 64, 0, stream>>>(blocksum, nscan);
  scanC_kernel<<<nscan, 256, 0, stream>>>(deg, blocksum, row_start, dinv, n);
  fill_kernel<<<eb256, 256, 0, stream>>>(src, dst, slot, row_start, col, e);

  gemm_kernel<DIN, HID><<<gemm_blocks, 256, 0, stream>>>(x, W1, A, n);
  spmm_kernel<HID, true><<<spmm_blocks, 256, 0, stream>>>(A, row_start, deg, col, dinv, b1, B, n);
  gemm_kernel<HID, HID><<<gemm_blocks, 256, 0, stream>>>(B, W2, A, n);
  spmm_kernel<HID, true><<<spmm_blocks, 256, 0, stream>>>(A, row_start, deg, col, dinv, b2, B, n);
  gemm_kernel<HID, DOUT><<<gemm_blocks, 256, 0, stream>>>(B, W3, A, n);
  spmm_kernel<DOUT, false><<<spmm_blocks, 256, 0, stream>>>(A, row_start, deg, col, dinv, b3, (float*)d_out, n);
}